// Round 16
// baseline (51.948 us; speedup 1.0000x reference)
//
#include <hip/hip_runtime.h>
#include <float.h>

// loss = (1/(E(E-1))) * sum_{i,j: t_i != t_j} relu(pred[i,t_j] - (f_own[j]-1)) / (N[t_i] N[t_j])
// Identity: sum_{k<S} relu(p - thr_k) = S*p - sum_{k<S} min(p, thr_k) for any S >= cnt
// (FLT_MAX pads contribute exactly 0; all 64 slots pre-padded).
// Thread = class. Quads 0-3 in registers; quads 4..nq-1 via wave-uniform runtime tail
// loop (L1-hot reloads) -> low VGPR, no switch, no fallback, one body for any cnt <= 64.
// Diagonal (c == t_i) excluded in-loop. No same-address device atomics.

#define CCLS 1000
#define PADF 64     // float slots per class, all padded -> single path supports cnt <= 64
#define TPB 256
#define CCH 250     // classes per chunk -> 4 chunks
#define NCH 4
#define NRBLK 512   // row blocks per chunk: RPB = 12288/512 = 24
#define NBLK (NCH * NRBLK)
#define RMAX 32

__global__ void k_init(int* fill, float4* thrP4) {
    int t = blockIdx.x * 256 + threadIdx.x;
    if (t < CCLS) fill[t] = 0;
    if (t < CCLS * 16) {   // pre-pad ALL 64 slots of every class with FLT_MAX
        int c = t >> 4, q = t & 15;
        thrP4[c * (PADF / 4) + q] = make_float4(FLT_MAX, FLT_MAX, FLT_MAX, FLT_MAX);
    }
}

__global__ void k_scatter(const float* __restrict__ pred, const int* __restrict__ target,
                          int* fill, float* thrP, int B) {
    int j = blockIdx.x * 256 + threadIdx.x;
    if (j >= B) return;
    int tj = target[j];
    float fo = pred[(size_t)j * CCLS + tj];  // f_own[j]
    int pos = atomicAdd(&fill[tj], 1);       // scattered addresses, low contention
    if (pos < PADF) thrP[tj * PADF + pos] = fo - 1.0f;
}

#define MIN4(p, t) ((fminf(p, t.x) + fminf(p, t.y)) + (fminf(p, t.z) + fminf(p, t.w)))

__global__ __launch_bounds__(TPB, 8) void k_main(const float* __restrict__ pred,
        const int* __restrict__ target, const float* __restrict__ thrP,
        const int* __restrict__ fill,
        float* __restrict__ part, int B, int RPB) {
    __shared__ float2 rowWT[RMAX];   // (target_as_float, invN[target]) per row
    __shared__ float redL[TPB / 64];

    const int tid = threadIdx.x;
    const int chunk = blockIdx.x / NRBLK;
    const int rblk = blockIdx.x % NRBLK;
    const int c0 = chunk * CCH;
    const int rbase = rblk * RPB;
    const int rows = min(min(RPB, B - rbase), RMAX);

    for (int r = tid; r < rows; r += TPB) {
        int t = target[rbase + r];
        rowWT[r] = make_float2(__int_as_float(t), 1.0f / (float)fill[t]);
    }
    __syncthreads();

    const int ccS = min(tid, CCH - 1);
    const int c = c0 + ccS;
    const int cntR = fill[c];
    const int cnt = min(cntR, PADF);
    const float invc = (tid < CCH && cntR > 0) ? 1.0f / (float)cntR : 0.f;

    int wmx = cnt;                       // wave-uniform max count
    for (int o = 32; o; o >>= 1) wmx = max(wmx, __shfl_xor(wmx, o));

    const float4* tp4 = (const float4*)(thrP + (size_t)c * PADF);
    const float* pp = pred + (size_t)rbase * CCLS + c;
    float acc = 0.f;

    const int nq = max((wmx + 3) >> 2, 4);   // 4..16, wave-uniform
    const float fS = (float)(4 * nq);
    // quads 0-3 resident in registers (always valid: all 64 slots padded)
    const float4 t0 = tp4[0], t1 = tp4[1], t2 = tp4[2], t3 = tp4[3];

    int r = 0;
    for (; r + 4 <= rows; r += 4) {
        const float p0 = pp[(size_t)(r + 0) * CCLS];
        const float p1 = pp[(size_t)(r + 1) * CCLS];
        const float p2 = pp[(size_t)(r + 2) * CCLS];
        const float p3 = pp[(size_t)(r + 3) * CCLS];
        float a0 = MIN4(p0, t0) + MIN4(p0, t1) + MIN4(p0, t2) + MIN4(p0, t3);
        float a1 = MIN4(p1, t0) + MIN4(p1, t1) + MIN4(p1, t2) + MIN4(p1, t3);
        float a2 = MIN4(p2, t0) + MIN4(p2, t1) + MIN4(p2, t2) + MIN4(p2, t3);
        float a3 = MIN4(p3, t0) + MIN4(p3, t1) + MIN4(p3, t2) + MIN4(p3, t3);
        for (int q = 4; q < nq; ++q) {      // wave-uniform tail, L1/L2-hot 16B reloads
            const float4 tq = tp4[q];
            a0 += MIN4(p0, tq);
            a1 += MIN4(p1, tq);
            a2 += MIN4(p2, tq);
            a3 += MIN4(p3, tq);
        }
        const float2 w0 = rowWT[r + 0], w1 = rowWT[r + 1];
        const float2 w2 = rowWT[r + 2], w3 = rowWT[r + 3];
        const float s0 = (c != __float_as_int(w0.x)) ? w0.y : 0.f;
        const float s1 = (c != __float_as_int(w1.x)) ? w1.y : 0.f;
        const float s2 = (c != __float_as_int(w2.x)) ? w2.y : 0.f;
        const float s3 = (c != __float_as_int(w3.x)) ? w3.y : 0.f;
        acc = fmaf(fmaf(fS, p0, -a0), s0, acc);
        acc = fmaf(fmaf(fS, p1, -a1), s1, acc);
        acc = fmaf(fmaf(fS, p2, -a2), s2, acc);
        acc = fmaf(fmaf(fS, p3, -a3), s3, acc);
    }
    for (; r < rows; ++r) {
        const float p = pp[(size_t)r * CCLS];
        float a = MIN4(p, t0) + MIN4(p, t1) + MIN4(p, t2) + MIN4(p, t3);
        for (int q = 4; q < nq; ++q) {
            const float4 tq = tp4[q];
            a += MIN4(p, tq);
        }
        const float2 w = rowWT[r];
        const float s = (c != __float_as_int(w.x)) ? w.y : 0.f;
        acc = fmaf(fmaf(fS, p, -a), s, acc);
    }
    acc *= invc;

    for (int o = 32; o; o >>= 1) acc += __shfl_down(acc, o);
    if ((tid & 63) == 0) redL[tid >> 6] = acc;
    __syncthreads();
    if (tid == 0) {
        float ssum = 0.f;
#pragma unroll
        for (int k = 0; k < TPB / 64; ++k) ssum += redL[k];
        part[blockIdx.x] = ssum;          // plain store, no contention
    }
}

// Single-block streaming epilogue: reduce partials + E count. No dependent chains.
__global__ __launch_bounds__(1024) void k_final(const float* __restrict__ part,
        const int* __restrict__ fill, float* __restrict__ out) {
    __shared__ float wP[16];
    __shared__ int wE[16];
    const int tid = threadIdx.x;
    float sp = 0.f;
    for (int i = tid; i < NBLK; i += 1024) sp += part[i];
    int se = 0;
    for (int c = tid; c < CCLS; c += 1024) se += (fill[c] > 0) ? 1 : 0;
    for (int o = 32; o; o >>= 1) {
        sp += __shfl_down(sp, o);
        se += __shfl_down(se, o);
    }
    if ((tid & 63) == 0) { wP[tid >> 6] = sp; wE[tid >> 6] = se; }
    __syncthreads();
    if (tid == 0) {
        float tp = 0.f;
        int te = 0;
#pragma unroll
        for (int k = 0; k < 16; ++k) { tp += wP[k]; te += wE[k]; }
        float E = (float)te;
        out[0] = tp / (E * (E - 1.0f));
    }
}

extern "C" void kernel_launch(void* const* d_in, const int* in_sizes, int n_in,
                              void* d_out, int out_size, void* d_ws, size_t ws_size,
                              hipStream_t stream) {
    const float* pred = (const float*)d_in[0];
    const int* target = (const int*)d_in[1];
    const int B = in_sizes[1];  // 12288

    char* ws = (char*)d_ws;
    int* fill   = (int*)(ws + 0);        // 1000 ints
    float* part = (float*)(ws + 4096);   // 2048 floats
    float* thrP = (float*)(ws + 16384);  // 1000*64 floats (256KB)

    const int gb = (B + 255) / 256;
    const int RPB = (B + NRBLK - 1) / NRBLK;

    k_init<<<(CCLS * 16 + 255) / 256, 256, 0, stream>>>(fill, (float4*)thrP);
    k_scatter<<<gb, 256, 0, stream>>>(pred, target, fill, thrP, B);
    k_main<<<NBLK, TPB, 0, stream>>>(pred, target, thrP, fill, part, B, RPB);
    k_final<<<1, 1024, 0, stream>>>(part, fill, (float*)d_out);
}

// Round 17
// 41.514 us; speedup vs baseline: 1.2514x; 1.2514x over previous
//
#include <hip/hip_runtime.h>
#include <float.h>

// loss = (1/(E(E-1))) * sum_{i,j: t_i != t_j} relu(pred[i,t_j] - (f_own[j]-1)) / (N[t_i] N[t_j])
// Identity: sum_{k<S} relu(p - thr_k) = S*p - sum_{k<S} min(p, thr_k) for any S >= cnt,
// with slots >= cnt masked to FLT_MAX AT LOAD TIME (once per thread, outside the row loop)
// -- no pre-pad kernel needed, unwritten ws poison never read.
// Thread = class; thresholds in float4 registers (R14's proven switch bodies; R15 showed
// in-loop tail reloads thrash L1 and serialize). Diagonal excluded in-loop.
// Chain: hipMemsetAsync(fill) + k_scatter + k_main + k_final. No same-address atomics.

#define CCLS 1000
#define PADF 64     // float slots per class (fallback supports count <= 64)
#define TPB 256
#define CCH 250     // classes per chunk -> 4 chunks
#define NCH 4
#define NRBLK 512   // row blocks per chunk: RPB = 12288/512 = 24
#define NBLK (NCH * NRBLK)
#define RMAX 32

__global__ void k_scatter(const float* __restrict__ pred, const int* __restrict__ target,
                          int* fill, float* thrP, int B) {
    int j = blockIdx.x * 256 + threadIdx.x;
    if (j >= B) return;
    int tj = target[j];
    float fo = pred[(size_t)j * CCLS + tj];  // f_own[j]
    int pos = atomicAdd(&fill[tj], 1);       // scattered addresses, low contention
    if (pos < PADF) thrP[tj * PADF + pos] = fo - 1.0f;
}

// Fully-static body: NQ float4 threshold registers (masked at load), 4-row batches.
#define BODYQ(NQ)                                                                   \
    {                                                                               \
        float4 tq[NQ];                                                              \
        _Pragma("unroll") for (int q = 0; q < NQ; ++q) {                            \
            float4 t = tp4[q];                                                      \
            t.x = (4 * q + 0 < cnt) ? t.x : FLT_MAX;                                \
            t.y = (4 * q + 1 < cnt) ? t.y : FLT_MAX;                                \
            t.z = (4 * q + 2 < cnt) ? t.z : FLT_MAX;                                \
            t.w = (4 * q + 3 < cnt) ? t.w : FLT_MAX;                                \
            tq[q] = t;                                                              \
        }                                                                           \
        const float fS = (float)(4 * NQ);                                           \
        int r = 0;                                                                  \
        _Pragma("unroll 1") for (; r + 4 <= rows; r += 4) {                         \
            const float p0 = pp[(size_t)(r + 0) * CCLS];                            \
            const float p1 = pp[(size_t)(r + 1) * CCLS];                            \
            const float p2 = pp[(size_t)(r + 2) * CCLS];                            \
            const float p3 = pp[(size_t)(r + 3) * CCLS];                            \
            float a0 = 0.f, a1 = 0.f, a2 = 0.f, a3 = 0.f;                           \
            _Pragma("unroll") for (int q = 0; q < NQ; ++q) {                        \
                a0 += (fminf(p0, tq[q].x) + fminf(p0, tq[q].y))                     \
                    + (fminf(p0, tq[q].z) + fminf(p0, tq[q].w));                    \
                a1 += (fminf(p1, tq[q].x) + fminf(p1, tq[q].y))                     \
                    + (fminf(p1, tq[q].z) + fminf(p1, tq[q].w));                    \
                a2 += (fminf(p2, tq[q].x) + fminf(p2, tq[q].y))                     \
                    + (fminf(p2, tq[q].z) + fminf(p2, tq[q].w));                    \
                a3 += (fminf(p3, tq[q].x) + fminf(p3, tq[q].y))                     \
                    + (fminf(p3, tq[q].z) + fminf(p3, tq[q].w));                    \
            }                                                                       \
            const float2 w0 = rowWT[r + 0], w1 = rowWT[r + 1];                      \
            const float2 w2 = rowWT[r + 2], w3 = rowWT[r + 3];                      \
            const float s0 = (c != __float_as_int(w0.x)) ? w0.y : 0.f;              \
            const float s1 = (c != __float_as_int(w1.x)) ? w1.y : 0.f;              \
            const float s2 = (c != __float_as_int(w2.x)) ? w2.y : 0.f;              \
            const float s3 = (c != __float_as_int(w3.x)) ? w3.y : 0.f;              \
            acc = fmaf(fmaf(fS, p0, -a0), s0, acc);                                 \
            acc = fmaf(fmaf(fS, p1, -a1), s1, acc);                                 \
            acc = fmaf(fmaf(fS, p2, -a2), s2, acc);                                 \
            acc = fmaf(fmaf(fS, p3, -a3), s3, acc);                                 \
        }                                                                           \
        for (; r < rows; ++r) {                                                     \
            const float p = pp[(size_t)r * CCLS];                                   \
            float a = 0.f;                                                          \
            _Pragma("unroll") for (int q = 0; q < NQ; ++q) {                        \
                a += (fminf(p, tq[q].x) + fminf(p, tq[q].y))                        \
                   + (fminf(p, tq[q].z) + fminf(p, tq[q].w));                       \
            }                                                                       \
            const float2 w = rowWT[r];                                              \
            const float s = (c != __float_as_int(w.x)) ? w.y : 0.f;                 \
            acc = fmaf(fmaf(fS, p, -a), s, acc);                                    \
        }                                                                           \
    }

__global__ __launch_bounds__(TPB) void k_main(const float* __restrict__ pred,
        const int* __restrict__ target, const float* __restrict__ thrP,
        const int* __restrict__ fill,
        float* __restrict__ part, int B, int RPB) {
    __shared__ float2 rowWT[RMAX];   // (target_as_float, invN[target]) per row
    __shared__ float redL[TPB / 64];

    const int tid = threadIdx.x;
    const int chunk = blockIdx.x / NRBLK;
    const int rblk = blockIdx.x % NRBLK;
    const int c0 = chunk * CCH;
    const int rbase = rblk * RPB;
    const int rows = min(min(RPB, B - rbase), RMAX);

    for (int r = tid; r < rows; r += TPB) {
        int t = target[rbase + r];
        rowWT[r] = make_float2(__int_as_float(t), 1.0f / (float)fill[t]);
    }
    __syncthreads();

    const int ccS = min(tid, CCH - 1);
    const int c = c0 + ccS;
    const int cntR = fill[c];
    const int cnt = min(cntR, PADF);
    const float invc = (tid < CCH && cntR > 0) ? 1.0f / (float)cntR : 0.f;

    int wmx = cnt;                       // wave-uniform max count
    for (int o = 32; o; o >>= 1) wmx = max(wmx, __shfl_xor(wmx, o));

    const float4* tp4 = (const float4*)(thrP + (size_t)c * PADF);
    const float* pp = pred + (size_t)rbase * CCLS + c;
    float acc = 0.f;

    if (wmx <= 32) {
        const int nq = (wmx + 3) >> 2;   // 1..8, wave-uniform
        switch ((nq + 1) >> 1) {         // 2/4/6/8 quads
            case 0:
            case 1: BODYQ(2) break;
            case 2: BODYQ(4) break;
            case 3: BODYQ(6) break;
            default: BODYQ(8) break;
        }
    } else {
        // correctness fallback (some count in 33..64): reads only written slots k < cnt
        const float* tg = thrP + (size_t)c * PADF;
        for (int r = 0; r < rows; ++r) {
            const float p = pp[(size_t)r * CCLS];
            float s = 0.f;
            for (int k = 0; k < cnt; ++k) s += fminf(p, tg[k]);
            const float2 w = rowWT[r];
            const float ws = (c != __float_as_int(w.x)) ? w.y : 0.f;
            acc = fmaf(fmaf((float)cnt, p, -s), ws, acc);
        }
    }
    acc *= invc;

    for (int o = 32; o; o >>= 1) acc += __shfl_down(acc, o);
    if ((tid & 63) == 0) redL[tid >> 6] = acc;
    __syncthreads();
    if (tid == 0) {
        float ssum = 0.f;
#pragma unroll
        for (int k = 0; k < TPB / 64; ++k) ssum += redL[k];
        part[blockIdx.x] = ssum;          // plain store, no contention
    }
}

// Single-block streaming epilogue: reduce partials + E count. No dependent chains.
__global__ __launch_bounds__(1024) void k_final(const float* __restrict__ part,
        const int* __restrict__ fill, float* __restrict__ out) {
    __shared__ float wP[16];
    __shared__ int wE[16];
    const int tid = threadIdx.x;
    float sp = 0.f;
    for (int i = tid; i < NBLK; i += 1024) sp += part[i];
    int se = 0;
    for (int c = tid; c < CCLS; c += 1024) se += (fill[c] > 0) ? 1 : 0;
    for (int o = 32; o; o >>= 1) {
        sp += __shfl_down(sp, o);
        se += __shfl_down(se, o);
    }
    if ((tid & 63) == 0) { wP[tid >> 6] = sp; wE[tid >> 6] = se; }
    __syncthreads();
    if (tid == 0) {
        float tp = 0.f;
        int te = 0;
#pragma unroll
        for (int k = 0; k < 16; ++k) { tp += wP[k]; te += wE[k]; }
        float E = (float)te;
        out[0] = tp / (E * (E - 1.0f));
    }
}

extern "C" void kernel_launch(void* const* d_in, const int* in_sizes, int n_in,
                              void* d_out, int out_size, void* d_ws, size_t ws_size,
                              hipStream_t stream) {
    const float* pred = (const float*)d_in[0];
    const int* target = (const int*)d_in[1];
    const int B = in_sizes[1];  // 12288

    char* ws = (char*)d_ws;
    int* fill   = (int*)(ws + 0);        // 1000 ints
    float* part = (float*)(ws + 4096);   // 2048 floats
    float* thrP = (float*)(ws + 16384);  // 1000*64 floats (256KB)

    const int gb = (B + 255) / 256;
    const int RPB = (B + NRBLK - 1) / NRBLK;

    hipMemsetAsync(fill, 0, CCLS * sizeof(int), stream);   // replaces k_init
    k_scatter<<<gb, 256, 0, stream>>>(pred, target, fill, thrP, B);
    k_main<<<NBLK, TPB, 0, stream>>>(pred, target, thrP, fill, part, B, RPB);
    k_final<<<1, 1024, 0, stream>>>(part, fill, (float*)d_out);
}